// Round 3
// baseline (202.384 us; speedup 1.0000x reference)
//
#include <hip/hip_runtime.h>
#include <math.h>

typedef __attribute__((ext_vector_type(8))) __bf16 bf16x8;
typedef __attribute__((ext_vector_type(4))) float f32x4;

#define PLANE 16384
#define ROWW 128

// ws float layout:
//   [0, 12288)     kern [b][c][12]  (first 9 used, padded for f4 alignment)
//   [12288, 13312) att  [b][128]
//   [13312, 21504) wfrag: 16384 ushorts (bf16). B-operand fragments of conv_w^T:
//                  frag[ot(8)][kc(4)][lane(64)][j(8)] = conv_w[ot*16+(lane&15)][kc*32+8*(lane>>4)+j]

__global__ __launch_bounds__(256) void precompute_kernel(
    const float* __restrict__ altitude,
    const float* __restrict__ W1,
    const float* __restrict__ W2,
    const float* __restrict__ ca_w1,
    const float* __restrict__ ca_w2,
    const float* __restrict__ conv_w,
    float* __restrict__ ws)
{
    int b = blockIdx.x;
    int t = threadIdx.x;
    __shared__ float alt_s[128];
    __shared__ float feat_s[128];
    __shared__ float a1_s[16];

    if (t < 128) alt_s[t] = altitude[b * 128 + t];
    __syncthreads();

    if (t < 128) {
        float s = 0.f;
        const float* wrow = W1 + t * 128;
        for (int j = 0; j < 128; ++j) s += alt_s[j] * wrow[j];
        feat_s[t] = (s >= 0.f) ? s : 0.1f * s;
    } else if (t < 144) {
        int r = t - 128;
        float s = 0.f;
        const float* wrow = ca_w1 + r * 128;
        for (int j = 0; j < 128; ++j) s += alt_s[j] * wrow[j];
        a1_s[r] = (s >= 0.f) ? s : 0.1f * s;
    }
    __syncthreads();

    // generated depthwise kernels -> padded [b][c][12]
    for (int m = t; m < 1152; m += 256) {
        float s = 0.f;
        const float* wrow = W2 + m * 128;
        for (int i = 0; i < 128; ++i) s += feat_s[i] * wrow[i];
        int c = m / 9, k = m % 9;
        ws[b * 1536 + c * 12 + k] = s;
    }
    // channel attention
    if (t < 128) {
        float s = 0.f;
        const float* wrow = ca_w2 + t * 16;
        for (int r = 0; r < 16; ++r) s += a1_s[r] * wrow[r];
        ws[12288 + b * 128 + t] = 1.f / (1.f + expf(-s));
    }
    // conv_w -> bf16 B-fragments (this block handles o-tile ot = b)
    {
        int kc   = t >> 6;
        int lane = t & 63;
        int o  = b * 16 + (lane & 15);
        int cb = kc * 32 + 8 * (lane >> 4);
        bf16x8 v;
        #pragma unroll
        for (int j = 0; j < 8; ++j)
            v[j] = (__bf16)conv_w[o * 128 + cb + j];
        ushort* wf = (ushort*)(ws + 13312);
        *reinterpret_cast<bf16x8*>(wf + ((size_t)(b * 4 + kc) * 64 + lane) * 8) = v;
    }
}

__global__ __launch_bounds__(256, 4) void fused_kernel(
    const float* __restrict__ x,
    const float* __restrict__ conv_b,
    const float* __restrict__ ws,
    float* __restrict__ out)
{
    const float* __restrict__ kern_w = ws;
    const float* __restrict__ att_w  = ws + 12288;
    const ushort* __restrict__ wfrag = (const ushort*)(ws + 13312);

    int bid = blockIdx.x;
    int b = bid & 7;          // XCD swizzle: each XCD streams one batch image
    int h = bid >> 3;         // row 0..127

    // dwT[px][c] bf16, row stride 136 ushorts (272B, 16B-aligned).
    // c stored in 16 chunks of 8, chunk index XOR-swizzled by (px>>3)&7.
    __shared__ __align__(16) ushort dwT[128 * 136];

    int t = threadIdx.x;
    const float* __restrict__ xb = x + (size_t)b * 128 * PLANE;

    // ---------------- Phase 1: depthwise 3x3 + ReLU -> dwT ----------------
    {
        int pg = t & 15;          // pixel group: px p0..p0+7
        int cg = t >> 4;          // channel group: c0..c0+7
        int p0 = pg * 8;
        int c0 = cg * 8;
        int b0 = (pg == 0)  ? 0   : p0 - 4;
        int b3 = (pg == 15) ? 124 : p0 + 8;
        bool hasT = (h > 0), hasB = (h < 127);
        float mT = hasT ? 1.f : 0.f;
        float mB = hasB ? 1.f : 0.f;
        int rT = hasT ? h - 1 : h;
        int rB = hasB ? h + 1 : h;

        bf16x8 bufv[8];   // [j] -> 8 bf16 along c (ci 0..7)

        #pragma unroll
        for (int ci = 0; ci < 8; ++ci) {
            int c = c0 + ci;
            const float* q  = xb + (size_t)c * PLANE;
            const float* kf = kern_w + b * 1536 + c * 12;
            float k0 = kf[0] * mT, k1 = kf[1] * mT, k2 = kf[2] * mT;
            float k3 = kf[3],      k4 = kf[4],      k5 = kf[5];
            float k6 = kf[6] * mB, k7 = kf[7] * mB, k8 = kf[8] * mB;

            const float* qT = q + rT * ROWW;
            const float* qC = q + h  * ROWW;
            const float* qB = q + rB * ROWW;

            float wT[16], wC[16], wB[16];
            {
                float4 f0 = *(const float4*)(qT + b0);
                float4 f1 = *(const float4*)(qT + p0);
                float4 f2 = *(const float4*)(qT + p0 + 4);
                float4 f3 = *(const float4*)(qT + b3);
                wT[0]=f0.x; wT[1]=f0.y; wT[2]=f0.z; wT[3]=f0.w;
                wT[4]=f1.x; wT[5]=f1.y; wT[6]=f1.z; wT[7]=f1.w;
                wT[8]=f2.x; wT[9]=f2.y; wT[10]=f2.z; wT[11]=f2.w;
                wT[12]=f3.x; wT[13]=f3.y; wT[14]=f3.z; wT[15]=f3.w;
            }
            {
                float4 f0 = *(const float4*)(qC + b0);
                float4 f1 = *(const float4*)(qC + p0);
                float4 f2 = *(const float4*)(qC + p0 + 4);
                float4 f3 = *(const float4*)(qC + b3);
                wC[0]=f0.x; wC[1]=f0.y; wC[2]=f0.z; wC[3]=f0.w;
                wC[4]=f1.x; wC[5]=f1.y; wC[6]=f1.z; wC[7]=f1.w;
                wC[8]=f2.x; wC[9]=f2.y; wC[10]=f2.z; wC[11]=f2.w;
                wC[12]=f3.x; wC[13]=f3.y; wC[14]=f3.z; wC[15]=f3.w;
            }
            {
                float4 f0 = *(const float4*)(qB + b0);
                float4 f1 = *(const float4*)(qB + p0);
                float4 f2 = *(const float4*)(qB + p0 + 4);
                float4 f3 = *(const float4*)(qB + b3);
                wB[0]=f0.x; wB[1]=f0.y; wB[2]=f0.z; wB[3]=f0.w;
                wB[4]=f1.x; wB[5]=f1.y; wB[6]=f1.z; wB[7]=f1.w;
                wB[8]=f2.x; wB[9]=f2.y; wB[10]=f2.z; wB[11]=f2.w;
                wB[12]=f3.x; wB[13]=f3.y; wB[14]=f3.z; wB[15]=f3.w;
            }
            if (pg == 0)  { wT[3]  = 0.f; wC[3]  = 0.f; wB[3]  = 0.f; }
            if (pg == 15) { wT[12] = 0.f; wC[12] = 0.f; wB[12] = 0.f; }

            #pragma unroll
            for (int j = 0; j < 8; ++j) {
                float s = wT[j+3]*k0 + wT[j+4]*k1 + wT[j+5]*k2
                        + wC[j+3]*k3 + wC[j+4]*k4 + wC[j+5]*k5
                        + wB[j+3]*k6 + wB[j+4]*k7 + wB[j+5]*k8;
                bufv[j][ci] = (__bf16)fmaxf(s, 0.f);
            }
        }

        int swz = pg & 7;
        #pragma unroll
        for (int j = 0; j < 8; ++j) {
            int w = p0 + j;
            *reinterpret_cast<bf16x8*>(&dwT[w * 136 + ((cg ^ swz) * 8)]) = bufv[j];
        }
    }
    __syncthreads();

    // ---------------- Phase 2: 1x1 conv via MFMA (D rows = px) + epilogue ----------------
    {
        int wid  = t >> 6;       // wave -> o range [wid*32, wid*32+32)
        int lane = t & 63;
        int r = lane & 15;
        int g = lane >> 4;

        // B fragments (conv_w^T), L2-resident
        bf16x8 bfr[2][4];
        #pragma unroll
        for (int ot = 0; ot < 2; ++ot)
            #pragma unroll
            for (int kc = 0; kc < 4; ++kc)
                bfr[ot][kc] = *reinterpret_cast<const bf16x8*>(
                    wfrag + ((size_t)((wid * 2 + ot) * 4 + kc) * 64 + lane) * 8);

        f32x4 acc[2][8];
        #pragma unroll
        for (int ot = 0; ot < 2; ++ot)
            #pragma unroll
            for (int pt = 0; pt < 8; ++pt)
                acc[ot][pt] = (f32x4){0.f, 0.f, 0.f, 0.f};

        #pragma unroll
        for (int pt = 0; pt < 8; ++pt) {
            int px = pt * 16 + r;
            int srow = px * 136;
            int s = (px >> 3) & 7;
            #pragma unroll
            for (int kc = 0; kc < 4; ++kc) {
                int chunk = kc * 4 + g;
                bf16x8 a = *reinterpret_cast<const bf16x8*>(
                    &dwT[srow + ((chunk ^ s) * 8)]);
                acc[0][pt] = __builtin_amdgcn_mfma_f32_16x16x32_bf16(a, bfr[0][kc], acc[0][pt], 0, 0, 0);
                acc[1][pt] = __builtin_amdgcn_mfma_f32_16x16x32_bf16(a, bfr[1][kc], acc[1][pt], 0, 0, 0);
            }
        }

        // epilogue: lane holds 4 consecutive px (regs) at channel o -> float4 I/O
        #pragma unroll
        for (int ot = 0; ot < 2; ++ot) {
            int o = wid * 32 + ot * 16 + r;
            float bi = conv_b[o];
            float at = att_w[b * 128 + o];
            size_t rowoff = (size_t)(b * 128 + o) * PLANE + (size_t)h * ROWW;
            const float* xrow = x + rowoff;
            float* orow = out + rowoff;
            #pragma unroll
            for (int pt = 0; pt < 8; ++pt) {
                int px = pt * 16 + g * 4;
                float4 xv = *(const float4*)(xrow + px);
                float4 ov;
                ov.x = acc[ot][pt][0] + bi + xv.x * at;
                ov.y = acc[ot][pt][1] + bi + xv.y * at;
                ov.z = acc[ot][pt][2] + bi + xv.z * at;
                ov.w = acc[ot][pt][3] + bi + xv.w * at;
                *(float4*)(orow + px) = ov;
            }
        }
    }
}

extern "C" void kernel_launch(void* const* d_in, const int* in_sizes, int n_in,
                              void* d_out, int out_size, void* d_ws, size_t ws_size,
                              hipStream_t stream) {
    (void)in_sizes; (void)n_in; (void)out_size; (void)ws_size;
    const float* x        = (const float*)d_in[0];
    const float* altitude = (const float*)d_in[1];
    const float* W1       = (const float*)d_in[2];
    const float* W2       = (const float*)d_in[3];
    const float* conv_w   = (const float*)d_in[4];
    const float* conv_b   = (const float*)d_in[5];
    const float* ca_w1    = (const float*)d_in[6];
    const float* ca_w2    = (const float*)d_in[7];
    float* out = (float*)d_out;
    float* ws  = (float*)d_ws;

    hipLaunchKernelGGL(precompute_kernel, dim3(8), dim3(256), 0, stream,
                       altitude, W1, W2, ca_w1, ca_w2, conv_w, ws);
    hipLaunchKernelGGL(fused_kernel, dim3(1024), dim3(256), 0, stream,
                       x, conv_b, ws, out);
}

// Round 4
// 74.562 us; speedup vs baseline: 2.7143x; 2.7143x over previous
//
#include <hip/hip_runtime.h>
#include <math.h>

typedef __attribute__((ext_vector_type(8))) __bf16 bf16x8;
typedef __attribute__((ext_vector_type(4))) float f32x4;

#define PLANE 16384
#define ROWW 128

// ws float layout:
//   [0, 12288)     kern [b][c][12]  (first 9 used, padded for f4 alignment)
//   [12288, 13312) att  [b][128]
//   [13312, 21504) wfrag: 16384 ushorts (bf16). B-operand fragments of conv_w^T:
//                  frag[ot(8)][kc(4)][lane(64)][j(8)] = conv_w[ot*16+(lane&15)][kc*32+8*(lane>>4)+j]

__global__ __launch_bounds__(256) void precompute_kernel(
    const float* __restrict__ altitude,
    const float* __restrict__ W1,
    const float* __restrict__ W2,
    const float* __restrict__ ca_w1,
    const float* __restrict__ ca_w2,
    const float* __restrict__ conv_w,
    float* __restrict__ ws)
{
    int b = blockIdx.x;
    int t = threadIdx.x;
    __shared__ float alt_s[128];
    __shared__ float feat_s[128];
    __shared__ float a1_s[16];

    if (t < 128) alt_s[t] = altitude[b * 128 + t];
    __syncthreads();

    if (t < 128) {
        float s = 0.f;
        const float* wrow = W1 + t * 128;
        for (int j = 0; j < 128; ++j) s += alt_s[j] * wrow[j];
        feat_s[t] = (s >= 0.f) ? s : 0.1f * s;
    } else if (t < 144) {
        int r = t - 128;
        float s = 0.f;
        const float* wrow = ca_w1 + r * 128;
        for (int j = 0; j < 128; ++j) s += alt_s[j] * wrow[j];
        a1_s[r] = (s >= 0.f) ? s : 0.1f * s;
    }
    __syncthreads();

    for (int m = t; m < 1152; m += 256) {
        float s = 0.f;
        const float* wrow = W2 + m * 128;
        for (int i = 0; i < 128; ++i) s += feat_s[i] * wrow[i];
        int c = m / 9, k = m % 9;
        ws[b * 1536 + c * 12 + k] = s;
    }
    if (t < 128) {
        float s = 0.f;
        const float* wrow = ca_w2 + t * 16;
        for (int r = 0; r < 16; ++r) s += a1_s[r] * wrow[r];
        ws[12288 + b * 128 + t] = 1.f / (1.f + expf(-s));
    }
    {
        int kc   = t >> 6;
        int lane = t & 63;
        int o  = b * 16 + (lane & 15);
        int cb = kc * 32 + 8 * (lane >> 4);
        bf16x8 v;
        #pragma unroll
        for (int j = 0; j < 8; ++j)
            v[j] = (__bf16)conv_w[o * 128 + cb + j];
        ushort* wf = (ushort*)(ws + 13312);
        *reinterpret_cast<bf16x8*>(wf + ((size_t)(b * 4 + kc) * 64 + lane) * 8) = v;
    }
}

__global__ __launch_bounds__(256, 4) void fused_kernel(
    const float* __restrict__ x,
    const float* __restrict__ conv_b,
    const float* __restrict__ ws,
    float* __restrict__ out)
{
    const float* __restrict__ kern_w = ws;
    const float* __restrict__ att_w  = ws + 12288;
    const ushort* __restrict__ wfrag = (const ushort*)(ws + 13312);

    int bid = blockIdx.x;
    int b = bid & 7;          // XCD swizzle: each XCD streams one batch image
    int h = bid >> 3;         // row 0..127

    // dwT[px][c] bf16, row stride 136 ushorts (272B = odd multiple of 16B -> bank spread).
    // c in 16 chunks of 8 bf16, chunk index XOR-swizzled by (px>>3)&7.
    __shared__ __align__(16) ushort dwT[128 * 136];

    int t = threadIdx.x;
    int pg = t & 31;          // 4-px group
    int cg = t >> 5;          // 16-ch group
    int p0 = pg * 4;
    int c0 = cg * 16;

    const float* __restrict__ xb = x + (size_t)b * 128 * PLANE;

    // ---------------- Phase 1: depthwise 3x3 + ReLU -> dwT (bf16) ----------------
    {
        int   rT = (h > 0)   ? h - 1 : h;
        int   rB = (h < 127) ? h + 1 : h;
        float mT = (h > 0)   ? 1.f : 0.f;
        float mB = (h < 127) ? 1.f : 0.f;
        int   lA = (p0 > 0)      ? p0 - 1 : 0;
        int   rA = (p0 + 4 < 128) ? p0 + 4 : 127;
        float mL = (p0 > 0)      ? 1.f : 0.f;
        float mR = (p0 + 4 < 128) ? 1.f : 0.f;

        bf16x8 bv[4][2];   // [px j][c half] — all indices literal below

        const float* kb = kern_w + b * 1536 + (size_t)c0 * 12;

#define ROWACC(RP, KL, KC, KR) {                                   \
        const float* rp_ = (RP);                                   \
        float4 m_ = *(const float4*)(rp_ + p0);                    \
        float  l_ = rp_[lA] * mL;                                  \
        float  r_ = rp_[rA] * mR;                                  \
        o0 = fmaf((KL), l_,   fmaf((KC), m_.x, fmaf((KR), m_.y, o0))); \
        o1 = fmaf((KL), m_.x, fmaf((KC), m_.y, fmaf((KR), m_.z, o1))); \
        o2 = fmaf((KL), m_.y, fmaf((KC), m_.z, fmaf((KR), m_.w, o2))); \
        o3 = fmaf((KL), m_.z, fmaf((KC), m_.w, fmaf((KR), r_,   o3))); }

#define DW_CH(CI) {                                                \
        const float* q_ = xb + (size_t)(c0 + (CI)) * PLANE;        \
        float4 kA = *(const float4*)(kb + (CI) * 12);              \
        float4 kB = *(const float4*)(kb + (CI) * 12 + 4);          \
        float  k8 = kb[(CI) * 12 + 8];                             \
        float o0 = 0.f, o1 = 0.f, o2 = 0.f, o3 = 0.f;              \
        ROWACC(q_ + rT * ROWW, kA.x * mT, kA.y * mT, kA.z * mT);   \
        ROWACC(q_ + h  * ROWW, kA.w,      kB.x,      kB.y);        \
        ROWACC(q_ + rB * ROWW, kB.z * mB, kB.w * mB, k8 * mB);     \
        bv[0][(CI) >> 3][(CI) & 7] = (__bf16)fmaxf(o0, 0.f);       \
        bv[1][(CI) >> 3][(CI) & 7] = (__bf16)fmaxf(o1, 0.f);       \
        bv[2][(CI) >> 3][(CI) & 7] = (__bf16)fmaxf(o2, 0.f);       \
        bv[3][(CI) >> 3][(CI) & 7] = (__bf16)fmaxf(o3, 0.f); }

        DW_CH(0)  DW_CH(1)  DW_CH(2)  DW_CH(3)
        DW_CH(4)  DW_CH(5)  DW_CH(6)  DW_CH(7)
        DW_CH(8)  DW_CH(9)  DW_CH(10) DW_CH(11)
        DW_CH(12) DW_CH(13) DW_CH(14) DW_CH(15)
#undef DW_CH
#undef ROWACC

        int s = (pg >> 1) & 7;
        #pragma unroll
        for (int j = 0; j < 4; ++j) {
            int px = p0 + j;
            *reinterpret_cast<bf16x8*>(&dwT[px * 136 + (((cg * 2 + 0) ^ s) * 8)]) = bv[j][0];
            *reinterpret_cast<bf16x8*>(&dwT[px * 136 + (((cg * 2 + 1) ^ s) * 8)]) = bv[j][1];
        }
    }
    __syncthreads();
    __builtin_amdgcn_sched_barrier(0);

    // ---------------- Phase 2: 1x1 conv via MFMA (D rows = px) + epilogue ----------------
    {
        int wid  = t >> 6;
        int lane = t & 63;
        int r = lane & 15;
        int g = lane >> 4;

        for (int ot = 0; ot < 2; ++ot) {
            int otile = wid * 2 + ot;

            bf16x8 bfr[4];
            #pragma unroll
            for (int kc = 0; kc < 4; ++kc)
                bfr[kc] = *reinterpret_cast<const bf16x8*>(
                    wfrag + ((size_t)(otile * 4 + kc) * 64 + lane) * 8);

            f32x4 acc[8];
            #pragma unroll
            for (int pt = 0; pt < 8; ++pt) acc[pt] = (f32x4){0.f, 0.f, 0.f, 0.f};

            #pragma unroll
            for (int pt = 0; pt < 8; ++pt) {
                int px = pt * 16 + r;
                int srow = px * 136;
                int s2 = (px >> 3) & 7;
                #pragma unroll
                for (int kc = 0; kc < 4; ++kc) {
                    bf16x8 a = *reinterpret_cast<const bf16x8*>(
                        &dwT[srow + (((kc * 4 + g) ^ s2) * 8)]);
                    acc[pt] = __builtin_amdgcn_mfma_f32_16x16x32_bf16(a, bfr[kc], acc[pt], 0, 0, 0);
                }
            }

            int o = otile * 16 + r;
            float bi = conv_b[o];
            float at = att_w[b * 128 + o];
            size_t rowoff = (size_t)(b * 128 + o) * PLANE + (size_t)h * ROWW;
            const float* xrow = x + rowoff;
            float* orow = out + rowoff;
            #pragma unroll
            for (int pt = 0; pt < 8; ++pt) {
                int px = pt * 16 + g * 4;
                float4 xv = *(const float4*)(xrow + px);
                float4 ov;
                ov.x = acc[pt][0] + bi + xv.x * at;
                ov.y = acc[pt][1] + bi + xv.y * at;
                ov.z = acc[pt][2] + bi + xv.z * at;
                ov.w = acc[pt][3] + bi + xv.w * at;
                *(float4*)(orow + px) = ov;
            }
        }
    }
}

extern "C" void kernel_launch(void* const* d_in, const int* in_sizes, int n_in,
                              void* d_out, int out_size, void* d_ws, size_t ws_size,
                              hipStream_t stream) {
    (void)in_sizes; (void)n_in; (void)out_size; (void)ws_size;
    const float* x        = (const float*)d_in[0];
    const float* altitude = (const float*)d_in[1];
    const float* W1       = (const float*)d_in[2];
    const float* W2       = (const float*)d_in[3];
    const float* conv_w   = (const float*)d_in[4];
    const float* conv_b   = (const float*)d_in[5];
    const float* ca_w1    = (const float*)d_in[6];
    const float* ca_w2    = (const float*)d_in[7];
    float* out = (float*)d_out;
    float* ws  = (float*)d_ws;

    hipLaunchKernelGGL(precompute_kernel, dim3(8), dim3(256), 0, stream,
                       altitude, W1, W2, ca_w1, ca_w2, conv_w, ws);
    hipLaunchKernelGGL(fused_kernel, dim3(1024), dim3(256), 0, stream,
                       x, conv_b, ws, out);
}